// Round 5
// baseline (2234.015 us; speedup 1.0000x reference)
//
#include <hip/hip_runtime.h>

// MultiTaskGRUAttn: 2-layer bi-GRU (B=64,T=1024,D=64,H=128) + attn pooling + heads.
// Full fp32 end-to-end; OUTPUT WRITTEN AS FP32 (reference output dtype is float32).
// ws: z1 | z2 | gi chunk | hstate (fp32, GB/Tc adaptive).

typedef unsigned short u16;

// ---------------------------------------------------------------------------
// fp32 tiled GEMM: gi[dir][ml][384] = A[g][K] @ W_dir^T + bias.
// ml local row, g = (ml>>lTc)*1024 + t0(dir) + (ml&(Tc-1)).
// grid (GB*Tc/64, 6, 2), block 256 (16x16 threads, 4x4 outputs each), K-chunks of 32.
// ---------------------------------------------------------------------------
__global__ __launch_bounds__(256) void proj_f32(
    const float* __restrict__ A, const float* __restrict__ Wf, const float* __restrict__ Wb,
    const float* __restrict__ bf_, const float* __restrict__ bb_,
    float* __restrict__ gi, int K, int t0f, int t0b, int lTc, int GB)
{
  const int N = 384;
  int Tc = 1 << lTc;
  int dir = blockIdx.z;
  const float* __restrict__ W    = dir ? Wb  : Wf;
  const float* __restrict__ bias = dir ? bb_ : bf_;
  int t0 = dir ? t0b : t0f;
  float* __restrict__ o = gi + (size_t)dir * GB * Tc * N;

  __shared__ float As[32][64];   // [k][m]
  __shared__ float Bs[32][64];   // [k][n]

  int tid = threadIdx.x;
  int tx = tid & 15, ty = tid >> 4;
  int m0 = blockIdx.x * 64;
  int n0 = blockIdx.y * 64;

  int srow = tid >> 2;           // 0..63
  int scol = (tid & 3) * 8;      // 0,8,16,24

  int mlA = m0 + srow;
  size_t gA = (size_t)(mlA >> lTc) * 1024 + t0 + (mlA & (Tc - 1));
  const float* arow = A + gA * K;
  const float* wrow = W + (size_t)(n0 + srow) * K;

  float acc[4][4];
#pragma unroll
  for (int i = 0; i < 4; i++)
#pragma unroll
    for (int j = 0; j < 4; j++) acc[i][j] = 0.f;

  for (int kk = 0; kk < K; kk += 32) {
    float4 a0 = *(const float4*)(arow + kk + scol);
    float4 a1 = *(const float4*)(arow + kk + scol + 4);
    float4 b0 = *(const float4*)(wrow + kk + scol);
    float4 b1 = *(const float4*)(wrow + kk + scol + 4);
    __syncthreads();             // previous iteration's reads complete
    As[scol + 0][srow] = a0.x; As[scol + 1][srow] = a0.y;
    As[scol + 2][srow] = a0.z; As[scol + 3][srow] = a0.w;
    As[scol + 4][srow] = a1.x; As[scol + 5][srow] = a1.y;
    As[scol + 6][srow] = a1.z; As[scol + 7][srow] = a1.w;
    Bs[scol + 0][srow] = b0.x; Bs[scol + 1][srow] = b0.y;
    Bs[scol + 2][srow] = b0.z; Bs[scol + 3][srow] = b0.w;
    Bs[scol + 4][srow] = b1.x; Bs[scol + 5][srow] = b1.y;
    Bs[scol + 6][srow] = b1.z; Bs[scol + 7][srow] = b1.w;
    __syncthreads();
#pragma unroll
    for (int k = 0; k < 32; k++) {
      float4 av = *(const float4*)&As[k][ty * 4];   // broadcast across tx
      float4 bv = *(const float4*)&Bs[k][tx * 4];
      float am[4] = {av.x, av.y, av.z, av.w};
      float bn[4] = {bv.x, bv.y, bv.z, bv.w};
#pragma unroll
      for (int i = 0; i < 4; i++)
#pragma unroll
        for (int j = 0; j < 4; j++) acc[i][j] = fmaf(am[i], bn[j], acc[i][j]);
    }
  }
#pragma unroll
  for (int i = 0; i < 4; i++) {
    size_t m = (size_t)(m0 + ty * 4 + i);
#pragma unroll
    for (int j = 0; j < 4; j++) {
      int n = n0 + tx * 4 + j;
      o[m * N + n] = acc[i][j] + bias[n];
    }
  }
}

// ---------------------------------------------------------------------------
// GRU recurrence over one Tc-step chunk, all fp32. One block per (sample, dir).
// unit i = tid&127, K-half = tid>>7; 3 Whh row-halves (192 fp32) in VGPRs;
// h fp32 double-buffered in LDS; gi prefetch 2 deep; h carried via hstate.
// ---------------------------------------------------------------------------
__global__ __launch_bounds__(256, 1) void gru_recur(
    const float* __restrict__ whhf, const float* __restrict__ whhb,
    const float* __restrict__ bhhf, const float* __restrict__ bhhb,
    const float* __restrict__ gi, float* __restrict__ zout,
    float* __restrict__ hstate, int t0f, int t0b, int first, int Tc, int GB)
{
  const int H = 128, G = 384;
  int b   = blockIdx.x >> 1;
  int dir = blockIdx.x & 1;
  const float* __restrict__ whh = dir ? whhb : whhf;
  const float* __restrict__ bhh = dir ? bhhb : bhhf;
  int t0 = dir ? t0b : t0f;
  int tid  = threadIdx.x;
  int i    = tid & 127;
  int half = tid >> 7;

  float wr[64], wz[64], wn[64];
  {
    const float* pr = whh + (size_t)i * H + half * 64;
    const float* pz = whh + (size_t)(H + i) * H + half * 64;
    const float* pn = whh + (size_t)(2 * H + i) * H + half * 64;
#pragma unroll
    for (int k = 0; k < 64; k += 4) {
      float4 vr = *(const float4*)(pr + k);
      float4 vz = *(const float4*)(pz + k);
      float4 vn = *(const float4*)(pn + k);
      wr[k] = vr.x; wr[k+1] = vr.y; wr[k+2] = vr.z; wr[k+3] = vr.w;
      wz[k] = vz.x; wz[k+1] = vz.y; wz[k+2] = vz.z; wz[k+3] = vz.w;
      wn[k] = vn.x; wn[k+1] = vn.y; wn[k+2] = vn.z; wn[k+3] = vn.w;
    }
  }
  float br = bhh[i], bz = bhh[H + i], bn = bhh[2 * H + i];

  __shared__ __align__(16) float hbuf[2][128];
  __shared__ float pbuf[128][3];

  float* hs = hstate + (size_t)(dir * GB + b) * H;
  float h = 0.f;
  if (first) {
    if (tid < H) { hbuf[0][tid] = 0.f; hbuf[1][tid] = 0.f; }
  } else {
    if (tid < H) hbuf[0][tid] = hs[tid];
    if (half == 0) h = hs[i];
  }

  const float* girow = gi + ((size_t)dir * GB + b) * Tc * G;  // [tt][384]
  float r0r = 0, r0z = 0, r0n = 0, r1r = 0, r1z = 0, r1n = 0;
  if (half == 0) {
    int tt0 = dir ? (Tc - 1) : 0;
    int tt1 = dir ? (Tc - 2) : 1;
    r0r = girow[(size_t)tt0 * G + i];
    r0z = girow[(size_t)tt0 * G + H + i];
    r0n = girow[(size_t)tt0 * G + 2 * H + i];
    r1r = girow[(size_t)tt1 * G + i];
    r1z = girow[(size_t)tt1 * G + H + i];
    r1n = girow[(size_t)tt1 * G + 2 * H + i];
  }
  __syncthreads();

  for (int s = 0; s < Tc; s++) {
    int cur = s & 1;
    float n2r = 0, n2z = 0, n2n = 0;
    if (half == 0 && s < Tc - 2) {               // prefetch gi for step s+2
      int tt2 = dir ? (Tc - 3 - s) : (s + 2);
      const float* gp = girow + (size_t)tt2 * G;
      n2r = gp[i]; n2z = gp[H + i]; n2n = gp[2 * H + i];
    }
    float ar = 0.f, az = 0.f, an = 0.f;
    const float* hc = &hbuf[cur][half * 64];
#pragma unroll
    for (int k = 0; k < 64; k += 4) {
      float4 hv = *(const float4*)(hc + k);      // LDS broadcast read
      ar = fmaf(wr[k], hv.x, ar);   az = fmaf(wz[k], hv.x, az);   an = fmaf(wn[k], hv.x, an);
      ar = fmaf(wr[k+1], hv.y, ar); az = fmaf(wz[k+1], hv.y, az); an = fmaf(wn[k+1], hv.y, an);
      ar = fmaf(wr[k+2], hv.z, ar); az = fmaf(wz[k+2], hv.z, az); an = fmaf(wn[k+2], hv.z, an);
      ar = fmaf(wr[k+3], hv.w, ar); az = fmaf(wz[k+3], hv.w, az); an = fmaf(wn[k+3], hv.w, an);
    }
    if (half == 1) { pbuf[i][0] = ar; pbuf[i][1] = az; pbuf[i][2] = an; }
    __syncthreads();
    if (half == 0) {
      int tt = dir ? (Tc - 1 - s) : s;
      int t_abs = t0 + tt;
      float grh = ar + pbuf[i][0] + br;
      float gzh = az + pbuf[i][1] + bz;
      float gnh = an + pbuf[i][2] + bn;
      float rg = 1.f / (1.f + __expf(-(r0r + grh)));
      float zg = 1.f / (1.f + __expf(-(r0z + gzh)));
      float npre = r0n + rg * gnh;
      float e  = __expf(-2.f * fabsf(npre));     // tanh, overflow-safe
      float nv = (1.f - e) / (1.f + e);
      nv = (npre < 0.f) ? -nv : nv;
      h = nv + zg * (h - nv);                    // (1-z)*n + z*h
      hbuf[cur ^ 1][i] = h;
      zout[((size_t)b * 1024 + t_abs) * 256 + dir * H + i] = h;
      r0r = r1r; r0z = r1z; r0n = r1n;
      r1r = n2r; r1z = n2z; r1n = n2n;
    }
    __syncthreads();
  }
  if (half == 0) hs[i] = h;                      // carry state to next chunk
}

// ---------------------------------------------------------------------------
// Attention pooling + heads (fp32 in, FP32 OUT). One block per sample in group.
// ---------------------------------------------------------------------------
__global__ __launch_bounds__(256) void pool_heads(
    const float* __restrict__ z2, const float* __restrict__ attn_w, const float* __restrict__ attn_b,
    const float* __restrict__ motor_w, const float* __restrict__ motor_b,
    const float* __restrict__ state_w, const float* __restrict__ state_b,
    const int* __restrict__ motor_k, float* __restrict__ out, int bbase)
{
  const int T = 1024, D2 = 256;
  int bl = blockIdx.x;
  int babs = bbase + bl;
  const float* Z = z2 + (size_t)bl * T * D2;
  __shared__ float sc[1024];
  __shared__ float red[8];
  __shared__ float pooled[256];
  int tid = threadIdx.x, lane = tid & 63, wv = tid >> 6;

  float aw0 = attn_w[lane],       aw1 = attn_w[64 + lane];
  float aw2 = attn_w[128 + lane], aw3 = attn_w[192 + lane];
  float ab = attn_b[0];
  for (int t = wv; t < T; t += 4) {
    const float* zr = Z + (size_t)t * D2;
    float s = zr[lane] * aw0 + zr[64 + lane] * aw1
            + zr[128 + lane] * aw2 + zr[192 + lane] * aw3;
#pragma unroll
    for (int off = 32; off; off >>= 1) s += __shfl_down(s, off);
    if (lane == 0) sc[t] = s + ab;
  }
  __syncthreads();

  float m = -3.0e38f;
  for (int t = tid; t < T; t += 256) m = fmaxf(m, sc[t]);
#pragma unroll
  for (int off = 32; off; off >>= 1) m = fmaxf(m, __shfl_down(m, off));
  if (lane == 0) red[wv] = m;
  __syncthreads();
  m = fmaxf(fmaxf(red[0], red[1]), fmaxf(red[2], red[3]));
  float sum = 0.f;
  for (int t = tid; t < T; t += 256) { float e = __expf(sc[t] - m); sc[t] = e; sum += e; }
#pragma unroll
  for (int off = 32; off; off >>= 1) sum += __shfl_down(sum, off);
  if (lane == 0) red[4 + wv] = sum;
  __syncthreads();
  float S = red[4] + red[5] + red[6] + red[7];
  float inv = 1.f / S;

  float acc = 0.f;
  for (int t = 0; t < T; t++) acc = fmaf(sc[t], Z[(size_t)t * D2 + tid], acc);
  pooled[tid] = acc * inv;
  __syncthreads();

  int o = tid >> 5, sl = tid & 31;
  if (o < 7) {
    int mk = motor_k[babs];
    const float* wp; float bias;
    if (o < 5) { wp = motor_w + o * D2;                          bias = motor_b[o]; }
    else       { wp = state_w + ((size_t)mk * 2 + (o - 5)) * D2; bias = state_b[mk * 2 + (o - 5)]; }
    float s = 0.f;
    for (int d = sl; d < D2; d += 32) s += pooled[d] * wp[d];
#pragma unroll
    for (int off = 16; off; off >>= 1) s += __shfl_down(s, off);
    if (sl == 0) {
      float v = s + bias;
      if (o < 5) out[babs * 5 + o] = v;
      else       out[320 + babs * 2 + (o - 5)] = v;
    }
  }
}

extern "C" void kernel_launch(void* const* d_in, const int* in_sizes, int n_in,
                              void* d_out, int out_size, void* d_ws, size_t ws_size,
                              hipStream_t stream) {
  const float* x       = (const float*)d_in[0];
  const int*   motor_k = (const int*)d_in[1];
  const float* wih_l0f = (const float*)d_in[2];
  const float* whh_l0f = (const float*)d_in[3];
  const float* bih_l0f = (const float*)d_in[4];
  const float* bhh_l0f = (const float*)d_in[5];
  const float* wih_l0b = (const float*)d_in[6];
  const float* whh_l0b = (const float*)d_in[7];
  const float* bih_l0b = (const float*)d_in[8];
  const float* bhh_l0b = (const float*)d_in[9];
  const float* wih_l1f = (const float*)d_in[10];
  const float* whh_l1f = (const float*)d_in[11];
  const float* bih_l1f = (const float*)d_in[12];
  const float* bhh_l1f = (const float*)d_in[13];
  const float* wih_l1b = (const float*)d_in[14];
  const float* whh_l1b = (const float*)d_in[15];
  const float* bih_l1b = (const float*)d_in[16];
  const float* bhh_l1b = (const float*)d_in[17];
  const float* attn_w  = (const float*)d_in[18];
  const float* attn_b  = (const float*)d_in[19];
  const float* motor_w = (const float*)d_in[20];
  const float* motor_b = (const float*)d_in[21];
  const float* state_w = (const float*)d_in[22];
  const float* state_b = (const float*)d_in[23];

  // Pick (batch-group GB, time-chunk Tc) to fit ws_size (all fp32).
  static const int candGB[9] = {64,32,16,8,4,2,1,1,1};
  static const int candTc[9] = {256,256,256,256,256,256,256,128,64};
  int GB = 1, Tc = 64;
  for (int c = 0; c < 9; c++) {
    size_t nb = (size_t)candGB[c] * 1024 * 256 * 4 * 2                // z1+z2 fp32
              + (size_t)2 * candGB[c] * candTc[c] * 384 * 4           // gi chunk fp32
              + (size_t)2 * candGB[c] * 128 * 4;                      // hstate
    if (nb <= ws_size) { GB = candGB[c]; Tc = candTc[c]; break; }
  }
  int lTc = 31 - __builtin_clz((unsigned)Tc);
  int nc = 1024 / Tc;

  float* z1 = (float*)d_ws;
  float* z2 = z1 + (size_t)GB * 1024 * 256;
  float* gi = z2 + (size_t)GB * 1024 * 256;
  float* hstate = gi + (size_t)2 * GB * Tc * 384;

  dim3 gpb((unsigned)(GB * Tc / 64), 6, 2);
  for (int gb = 0; gb < 64 / GB; gb++) {
    const float* xg = x + (size_t)gb * GB * 1024 * 64;
    for (int c = 0; c < nc; c++) {
      int t0f = c * Tc, t0b = (nc - 1 - c) * Tc;
      proj_f32<<<gpb, 256, 0, stream>>>(xg, wih_l0f, wih_l0b, bih_l0f, bih_l0b,
                                        gi, 64, t0f, t0b, lTc, GB);
      gru_recur<<<2 * GB, 256, 0, stream>>>(whh_l0f, whh_l0b, bhh_l0f, bhh_l0b, gi, z1,
                                            hstate, t0f, t0b, c == 0, Tc, GB);
    }
    for (int c = 0; c < nc; c++) {
      int t0f = c * Tc, t0b = (nc - 1 - c) * Tc;
      proj_f32<<<gpb, 256, 0, stream>>>(z1, wih_l1f, wih_l1b, bih_l1f, bih_l1b,
                                        gi, 256, t0f, t0b, lTc, GB);
      gru_recur<<<2 * GB, 256, 0, stream>>>(whh_l1f, whh_l1b, bhh_l1f, bhh_l1b, gi, z2,
                                            hstate, t0f, t0b, c == 0, Tc, GB);
    }
    pool_heads<<<GB, 256, 0, stream>>>(z2, attn_w, attn_b, motor_w, motor_b,
                                       state_w, state_b, motor_k, (float*)d_out, gb * GB);
  }
}